// Round 16
// baseline (47.922 us; speedup 1.0000x reference)
//
#include <hip/hip_runtime.h>

typedef __attribute__((ext_vector_type(8))) __bf16 bf16x8;
typedef __attribute__((ext_vector_type(4))) float f32x4;
typedef __attribute__((ext_vector_type(2))) float f32x2;

#define DI 512
#define DO 512
#define XROW (128 * DI)
#define OROW (128 * DO)
#define BK 32
#define BOFFB 8192           // buf: A bf16 [128][32] = 8 KB | B bf16 [256][32] = 16 KB
#define BUFSZ 24576

#define LGKM0()  asm volatile("s_waitcnt lgkmcnt(0)" ::: "memory")
#define SBAR()   __builtin_amdgcn_s_barrier()
#define SCHED0() __builtin_amdgcn_sched_barrier(0)

__global__ __launch_bounds__(512, 4)
void nlinear_mfma(const float* __restrict__ xp, const float* __restrict__ wp,
                  const float* __restrict__ bp, float* __restrict__ op) {
  // XCD swizzle (R10-proven): 512 blocks, 64 per XCD
  int blk = blockIdx.x;
  int L = ((blk & 7) << 6) + (blk >> 3);
  int n = L >> 2, mt = (L >> 1) & 1, ot = L & 1;
  int mBase = mt << 7, oBase = ot << 8;      // block tile: 128m x 256o

  __shared__ char lds[2 * BUFSZ];            // 48 KB -> still 2 blocks/CU (reg-capped)

  int tid = threadIdx.x, lane = tid & 63, wid = tid >> 6;
  int wm = (wid >> 2) << 6, wn = (wid & 3) << 6;   // wave tile 64m x 64o
  int l16 = lane & 15, l4 = lane >> 4;

  // A staging (NEW: bf16 via regs, replaces fp32 DMA): thread t -> row t>>2,
  // k-slot t&3 (8 consecutive k). 2 x f32x4 loads (lanes 0-3 cover 128B/row),
  // 4 cvt_pk, 1 b128 swizzled write. A LDS: [128 m][32 k] bf16, 64 B/row,
  // slot_phys = slot ^ ((row>>1)&3) -- same XOR family on write and read;
  // (row,slot) bijective -> uniform 8-accesses/bank on b128 ops.
  int arow = tid >> 2, aks = tid & 3;
  const float* aSrc = xp + (size_t)(mBase + arow) * XROW + n * DI + aks * 8;
  int aWr = arow * 64 + ((aks ^ ((arow >> 1) & 3)) << 4);

  f32x4 aRv[2];
  auto loadA = [&](int kt) {
    aRv[0] = *(const f32x4*)(aSrc + kt * BK);
    aRv[1] = *(const f32x4*)(aSrc + kt * BK + 4);
  };
  auto writeA = [&](int bufOff) {
    bf16x8 v;
    #pragma unroll
    for (int e = 0; e < 8; ++e) v[e] = (__bf16)aRv[e >> 2][e & 3];
    *(bf16x8*)(lds + bufOff + aWr) = v;
  };

  // B staging (R10-proven): thread t -> o-pair {2*(t&127), +1}, k-range
  // kq*8..+8; 8 x f32x2 loads, 2 x b128 k-contiguous swizzled writes.
  int bo2 = (tid & 127) << 1, kq = tid >> 7;
  const float* bSrc = wp + ((size_t)n * DI + (kq << 3)) * DO + oBase + bo2;
  int bWr0 = BOFFB + (bo2)     * 64 + ((kq ^ ((bo2 >> 1) & 3)) << 4);
  int bWr1 = BOFFB + (bo2 + 1) * 64 + ((kq ^ ((bo2 >> 1) & 3)) << 4);

  f32x2 bRv[8];
  auto loadB = [&](int kt) {
    #pragma unroll
    for (int j = 0; j < 8; ++j)
      bRv[j] = *(const f32x2*)(bSrc + (size_t)(kt * BK + j) * DO);
  };
  auto writeB = [&](int bufOff) {
    bf16x8 v0, v1;
    #pragma unroll
    for (int j = 0; j < 8; ++j) { v0[j] = (__bf16)bRv[j].x; v1[j] = (__bf16)bRv[j].y; }
    *(bf16x8*)(lds + bufOff + bWr0) = v0;
    *(bf16x8*)(lds + bufOff + bWr1) = v1;
  };

  f32x4 acc[4][4];
  #pragma unroll
  for (int i = 0; i < 4; ++i)
    #pragma unroll
    for (int j = 0; j < 4; ++j)
      acc[i][j] = f32x4{0.f, 0.f, 0.f, 0.f};

  // i-outer compute: bfr[4] resident (16 regs), af transient (4 regs).
  bf16x8 bfr[4];
  auto loadBfr = [&](int bufOff) {
    #pragma unroll
    for (int j = 0; j < 4; ++j) {
      int row = wn + j * 16 + l16;
      int slot = l4 ^ ((row >> 1) & 3);
      bfr[j] = *(const bf16x8*)(lds + bufOff + BOFFB + row * 64 + slot * 16);
    }
  };
  auto computeI = [&](int bufOff, int i) {
    int row = wm + i * 16 + l16;
    int slot = l4 ^ ((row >> 1) & 3);
    bf16x8 af = *(const bf16x8*)(lds + bufOff + row * 64 + slot * 16);
    #pragma unroll
    for (int j = 0; j < 4; ++j)
      acc[i][j] = __builtin_amdgcn_mfma_f32_16x16x32_bf16(af, bfr[j], acc[i][j], 0, 0, 0);
  };

  float bi[4];
  #pragma unroll
  for (int j = 0; j < 4; ++j)
    bi[j] = bp[n * DO + oBase + wn + j * 16 + l16];

  // ---- prologue: buf0 staged; tile1 loads in flight across the barrier ----
  loadA(0); loadB(0);
  writeA(0); writeB(0);        // auto-wait tile0 regs
  loadA(1); loadB(1);          // tile1: stalls once at iter0's write (accepted)
  SCHED0(); LGKM0(); SBAR(); SCHED0();

  // iter kt: write tile kt+1 (regs aged ~1 iter) -> nxt; issue tile kt+2
  // loads (age >=1.3 iters); compute cur (4 bfr + 4 af b128, 16 MFMA).
  // No manual vmcnt anywhere: write-side cvts auto-wait their own loads.
  for (int kt = 0; kt < 16; ++kt) {
    int cur = (kt & 1) * BUFSZ, nxt = cur ^ BUFSZ;
    if (kt < 15) { writeA(nxt); writeB(nxt); }
    if (kt < 14) { loadA(kt + 2); loadB(kt + 2); }
    SCHED0();
    loadBfr(cur);
    computeI(cur, 0);
    computeI(cur, 1);
    computeI(cur, 2);
    computeI(cur, 3);
    if (kt < 15) { SCHED0(); LGKM0(); SBAR(); SCHED0(); }
  }

  // epilogue: D layout col = lane&15, row = (lane>>4)*4 + r (m89-verified)
  #pragma unroll
  for (int i = 0; i < 4; ++i) {
    #pragma unroll
    for (int j = 0; j < 4; ++j) {
      #pragma unroll
      for (int r = 0; r < 4; ++r) {
        int m = mBase + wm + i * 16 + l4 * 4 + r;
        int o = oBase + wn + j * 16 + l16;
        op[(size_t)m * OROW + n * DO + o] = acc[i][j][r] + bi[j];
      }
    }
  }
}

extern "C" void kernel_launch(void* const* d_in, const int* in_sizes, int n_in,
                              void* d_out, int out_size, void* d_ws, size_t ws_size,
                              hipStream_t stream) {
  const float* x = (const float*)d_in[0];
  const float* w = (const float*)d_in[1];
  const float* b = (const float*)d_in[2];
  float* o = (float*)d_out;
  hipLaunchKernelGGL(nlinear_mfma, dim3(512), dim3(512), 0, stream, x, w, b, o);
}